// Round 1
// baseline (1353.697 us; speedup 1.0000x reference)
//
#include <hip/hip_runtime.h>
#include <hip/hip_bf16.h>

// Problem constants: E=8, B=2, N=2048, D=1024, F=4096. M per expert = B*N = 4096.
#define NE 8
#define DD 1024
#define FF 4096
#define MPE 4096

typedef __attribute__((ext_vector_type(8))) __bf16 bf16x8;
typedef __attribute__((ext_vector_type(4))) float f32x4;
typedef __attribute__((ext_vector_type(8))) unsigned short u16x8;

__device__ __forceinline__ unsigned short f2bf(float f) {
  union { float f; unsigned u; } cv; cv.f = f;
  unsigned u = cv.u;
  unsigned r = u + 0x7FFFu + ((u >> 16) & 1u);
  return (unsigned short)(r >> 16);
}

// jax.nn.gelu default = tanh approximation; tanh via exp, inf-safe at both tails.
__device__ __forceinline__ float gelu_f(float x) {
  float u = 1.5957691216057308f * (x + 0.044715f * x * x * x);
  float e = __expf(u);
  return x * (1.0f - 1.0f / (e + 1.0f));
}

__device__ __forceinline__ void gld16(const void* g, void* l) {
  __builtin_amdgcn_global_load_lds(
      (const __attribute__((address_space(1))) unsigned int*)g,
      (__attribute__((address_space(3))) unsigned int*)l,
      16, 0, 0);
}

// ---------------- fp32 -> bf16 convert (x) ----------------
__global__ __launch_bounds__(256) void experts_convert(
    const float* __restrict__ in, unsigned short* __restrict__ out, long n8) {
  long i = (long)blockIdx.x * 256 + threadIdx.x;
  if (i >= n8) return;
  const float4* p = (const float4*)in + i * 2;
  float4 a = p[0], b = p[1];
  u16x8 o;
  o[0] = f2bf(a.x); o[1] = f2bf(a.y); o[2] = f2bf(a.z); o[3] = f2bf(a.w);
  o[4] = f2bf(b.x); o[5] = f2bf(b.y); o[6] = f2bf(b.z); o[7] = f2bf(b.w);
  *((u16x8*)out + i) = o;
}

// ---------------- fp32 [E][R][C] -> bf16 [E][C][R] transpose+convert ----------------
__global__ __launch_bounds__(256) void experts_transpose(
    const float* __restrict__ in, unsigned short* __restrict__ out, int R, int C) {
  __shared__ unsigned short tile[32][33];
  const int e = blockIdx.z;
  const float* ip = in + (size_t)e * R * C;
  unsigned short* op = out + (size_t)e * R * C;
  const int c0 = blockIdx.x * 32, r0 = blockIdx.y * 32;
  const int tx = threadIdx.x, ty = threadIdx.y; // (32,8)
#pragma unroll
  for (int i = 0; i < 32; i += 8) {
    float v = ip[(size_t)(r0 + ty + i) * C + (c0 + tx)];
    tile[ty + i][tx] = f2bf(v);
  }
  __syncthreads();
#pragma unroll
  for (int i = 0; i < 32; i += 8) {
    op[(size_t)(c0 + ty + i) * R + (r0 + tx)] = tile[tx][ty + i];
  }
}

// ---------------- bf16 GEMM, B^T layout, m97-style 128x128x64 ----------------
// MODE 0: Out = bf16 h (ez-relative, oStride), epilogue gelu(acc+bias)
// MODE 1: Out = fp32 (absolute e*oStride), epilogue acc+bias
template <int MODE>
__global__ __launch_bounds__(256) void experts_gemm_bt(
    const unsigned short* __restrict__ A, const unsigned short* __restrict__ Bt,
    const float* __restrict__ bias, void* __restrict__ Out,
    const int K, const int N, const int e0, const size_t aStride, const size_t oStride) {
  const int tid = threadIdx.x;
  const int lane = tid & 63;
  const int wid = tid >> 6;
  const int wr = wid >> 1, wc = wid & 1;
  const int ez = blockIdx.z;
  const int e = e0 + ez;

  const unsigned short* Ae = A + (size_t)ez * aStride;
  const unsigned short* Be = Bt + (size_t)e * (size_t)N * (size_t)K;
  const float* be = bias + (size_t)e * N;

  const int bm = blockIdx.y * 128;
  const int bn = blockIdx.x * 128;

  __shared__ __align__(16) unsigned short As[128 * 64];
  __shared__ __align__(16) unsigned short Bs[128 * 64];

  f32x4 acc[4][4] = {};

  const int srow = tid >> 3;
  const int skel = (tid & 7) * 8;
  const unsigned short* ga = Ae + (size_t)(bm + srow) * K + skel;
  const unsigned short* gb = Be + (size_t)(bn + srow) * K + skel;
  char* asb = (char*)As + wid * 1024; // wave-uniform base; HW adds lane*16
  char* bsb = (char*)Bs + wid * 1024;

  for (int k0 = 0; k0 < K; k0 += 64) {
    __syncthreads();
#pragma unroll
    for (int c = 0; c < 4; ++c) {
      gld16(ga + (size_t)c * 32 * K + k0, asb + c * 4096);
      gld16(gb + (size_t)c * 32 * K + k0, bsb + c * 4096);
    }
    __syncthreads(); // vmcnt(0) drained before barrier -> tiles ready
#pragma unroll
    for (int ks = 0; ks < 2; ++ks) {
      bf16x8 af[4], bfr[4];
      const int kk = ks * 32 + (lane >> 4) * 8;
      const int ar = wr * 64 + (lane & 15);
      const int br = wc * 64 + (lane & 15);
#pragma unroll
      for (int i = 0; i < 4; ++i)
        af[i] = *reinterpret_cast<const bf16x8*>(&As[(ar + i * 16) * 64 + kk]);
#pragma unroll
      for (int i = 0; i < 4; ++i)
        bfr[i] = *reinterpret_cast<const bf16x8*>(&Bs[(br + i * 16) * 64 + kk]);
#pragma unroll
      for (int mi = 0; mi < 4; ++mi)
#pragma unroll
        for (int ni = 0; ni < 4; ++ni)
          acc[mi][ni] = __builtin_amdgcn_mfma_f32_16x16x32_bf16(
              af[mi], bfr[ni], acc[mi][ni], 0, 0, 0);
    }
  }

  const int orow0 = bm + wr * 64 + ((lane >> 4) << 2);
  const int ocol0 = bn + wc * 64 + (lane & 15);
  float bv[4];
#pragma unroll
  for (int ni = 0; ni < 4; ++ni) bv[ni] = be[ocol0 + ni * 16];

  if (MODE == 0) {
    unsigned short* O = (unsigned short*)Out + (size_t)ez * oStride;
#pragma unroll
    for (int mi = 0; mi < 4; ++mi)
#pragma unroll
      for (int r = 0; r < 4; ++r) {
        const size_t rowoff = (size_t)(orow0 + mi * 16 + r) * N;
#pragma unroll
        for (int ni = 0; ni < 4; ++ni) {
          float v = acc[mi][ni][r] + bv[ni];
          O[rowoff + ocol0 + ni * 16] = f2bf(gelu_f(v));
        }
      }
  } else {
    float* O = (float*)Out + (size_t)e * oStride;
#pragma unroll
    for (int mi = 0; mi < 4; ++mi)
#pragma unroll
      for (int r = 0; r < 4; ++r) {
        const size_t rowoff = (size_t)(orow0 + mi * 16 + r) * N;
#pragma unroll
        for (int ni = 0; ni < 4; ++ni) {
          O[rowoff + ocol0 + ni * 16] = acc[mi][ni][r] + bv[ni];
        }
      }
  }
}

extern "C" void kernel_launch(void* const* d_in, const int* in_sizes, int n_in,
                              void* d_out, int out_size, void* d_ws, size_t ws_size,
                              hipStream_t stream) {
  const float* x = (const float*)d_in[0];
  const float* w1 = (const float*)d_in[1];
  const float* b1 = (const float*)d_in[2];
  const float* w2 = (const float*)d_in[3];
  const float* b2 = (const float*)d_in[4];

  char* ws = (char*)d_ws;
  unsigned short* xbf = (unsigned short*)ws;                  // 64 MiB
  unsigned short* w1t = (unsigned short*)(ws + 67108864);     // 64 MiB  [E][F][D]
  unsigned short* w2t = (unsigned short*)(ws + 134217728);    // 64 MiB  [E][D][F]
  unsigned short* h   = (unsigned short*)(ws + 201326592);    // 256 MiB (full mode)

  experts_convert<<<16384, 256, 0, stream>>>(x, xbf, 4194304L);
  experts_transpose<<<dim3(FF / 32, DD / 32, NE), dim3(32, 8), 0, stream>>>(w1, w1t, DD, FF);
  experts_transpose<<<dim3(DD / 32, FF / 32, NE), dim3(32, 8), 0, stream>>>(w2, w2t, FF, DD);

  const bool full = ws_size >= 469762048ull;
  if (full) {
    experts_gemm_bt<0><<<dim3(FF / 128, MPE / 128, NE), 256, 0, stream>>>(
        xbf, w1t, b1, h, DD, FF, 0, (size_t)MPE * DD, (size_t)MPE * FF);
    experts_gemm_bt<1><<<dim3(DD / 128, MPE / 128, NE), 256, 0, stream>>>(
        h, w2t, b2, d_out, FF, DD, 0, (size_t)MPE * FF, (size_t)MPE * DD);
  } else {
    for (int e = 0; e < NE; ++e) {
      experts_gemm_bt<0><<<dim3(FF / 128, MPE / 128, 1), 256, 0, stream>>>(
          xbf + (size_t)e * MPE * DD, w1t, b1, h, DD, FF, e, 0, 0);
      experts_gemm_bt<1><<<dim3(DD / 128, MPE / 128, 1), 256, 0, stream>>>(
          h, w2t, b2, d_out, FF, DD, e, 0, (size_t)MPE * DD);
    }
  }
}

// Round 2
// 1039.390 us; speedup vs baseline: 1.3024x; 1.3024x over previous
//
#include <hip/hip_runtime.h>
#include <hip/hip_bf16.h>

// E=8, B=2, N=2048, D=1024, F=4096. M per expert = B*N = 4096.
#define NE 8
#define DD 1024
#define FF 4096
#define MPE 4096

typedef __attribute__((ext_vector_type(8))) __bf16 bf16x8;
typedef __attribute__((ext_vector_type(4))) float f32x4;
typedef __attribute__((ext_vector_type(8))) unsigned short u16x8;

__device__ __forceinline__ unsigned short f2bf(float f) {
  union { float f; unsigned u; } cv; cv.f = f;
  unsigned u = cv.u;
  unsigned r = u + 0x7FFFu + ((u >> 16) & 1u);
  return (unsigned short)(r >> 16);
}

// jax.nn.gelu default = tanh approximation; tanh via exp, inf-safe both tails.
__device__ __forceinline__ float gelu_f(float x) {
  float u = 1.5957691216057308f * (x + 0.044715f * x * x * x);
  float e = __expf(u);
  return x * (1.0f - 1.0f / (e + 1.0f));
}

__device__ __forceinline__ void gld16(const void* g, void* l) {
  __builtin_amdgcn_global_load_lds(
      (const __attribute__((address_space(1))) unsigned int*)g,
      (__attribute__((address_space(3))) unsigned int*)l,
      16, 0, 0);
}

__device__ __forceinline__ f32x4 MF(bf16x8 a, bf16x8 b, f32x4 c) {
  return __builtin_amdgcn_mfma_f32_16x16x32_bf16(a, b, c, 0, 0, 0);
}

// ---------------- fp32 -> bf16 convert (x) ----------------
__global__ __launch_bounds__(256) void experts_convert(
    const float* __restrict__ in, unsigned short* __restrict__ out, long n8) {
  long i = (long)blockIdx.x * 256 + threadIdx.x;
  if (i >= n8) return;
  const float4* p = (const float4*)in + i * 2;
  float4 a = p[0], b = p[1];
  u16x8 o;
  o[0] = f2bf(a.x); o[1] = f2bf(a.y); o[2] = f2bf(a.z); o[3] = f2bf(a.w);
  o[4] = f2bf(b.x); o[5] = f2bf(b.y); o[6] = f2bf(b.z); o[7] = f2bf(b.w);
  *((u16x8*)out + i) = o;
}

// ------- fp32 [E][R][C] -> bf16 [E][C][R] transpose+convert, 64x64 tiles -------
__global__ __launch_bounds__(256) void experts_transpose64(
    const float* __restrict__ in, unsigned short* __restrict__ out, int R, int C) {
  __shared__ unsigned short tile[64][73]; // stride 73: 4*73*2B -> bank step 18, 16 distinct
  const int e = blockIdx.z;
  const float* ip = in + (size_t)e * R * C;
  unsigned short* op = out + (size_t)e * R * C;
  const int c0 = blockIdx.x * 64, r0 = blockIdx.y * 64;
  const int tx = threadIdx.x & 63;
  const int ty = threadIdx.x >> 6; // 0..3
#pragma unroll
  for (int j = 0; j < 16; ++j) {
    int row = ty + j * 4;
    tile[row][tx] = f2bf(ip[(size_t)(r0 + row) * C + (c0 + tx)]);
  }
  __syncthreads();
  const int cc0 = threadIdx.x >> 4;      // 0..15
  const int rr = (threadIdx.x & 15) * 4; // 0..60
#pragma unroll
  for (int j = 0; j < 4; ++j) {
    int cc = cc0 + j * 16;
    ushort4 v;
    v.x = tile[rr][cc]; v.y = tile[rr + 1][cc];
    v.z = tile[rr + 2][cc]; v.w = tile[rr + 3][cc];
    *(ushort4*)&op[(size_t)(c0 + cc) * R + r0 + rr] = v;
  }
}

// ---------------- bf16 GEMM, B^T layout, 256x256 tile, BK=32, 4-slot ring ----------------
// 8 waves (2M x 4N), per-wave 128x64 output = acc[8][4] 16x16 frags.
// LDS: 4 slots x (A 16KB + B 16KB) = 128 KiB. Prefetch distance 3 K-tiles,
// counted vmcnt(8) steady state, one raw s_barrier per K-tile.
// Swizzle: 16B chunk index ^= (row & 3), applied on gld16 SOURCE and ds_read addr.
// MODE 0: Out bf16 (ez-relative, oStride), epilogue gelu(acc+bias)
// MODE 1: Out fp32 (absolute e*oStride), epilogue acc+bias
template <int MODE>
__global__ __launch_bounds__(512, 2) void experts_gemm8(
    const unsigned short* __restrict__ A, const unsigned short* __restrict__ Bt,
    const float* __restrict__ bias, void* __restrict__ Out,
    const int K, const int N, const int e0, const size_t aStride, const size_t oStride) {
  const int tid = threadIdx.x;
  const int lane = tid & 63;
  const int l15 = lane & 15;
  const int wid = tid >> 6; // 0..7
  const int wr = wid >> 2;  // 0..1 (M)
  const int wc = wid & 3;   // 0..3 (N)
  const int ez = blockIdx.z;
  const int e = e0 + ez;
  const int NT = K >> 5;

  const unsigned short* Ae = A + (size_t)ez * aStride;
  const unsigned short* Be = Bt + (size_t)e * (size_t)N * (size_t)K;
  const float* be = bias + (size_t)e * N;

  const int bm = blockIdx.y << 8;
  const int bn = blockIdx.x << 8;

  __shared__ __align__(16) unsigned short lds[65536]; // 128 KiB

  f32x4 acc[8][4] = {};

  // staging: thread covers LDS bytes d = c*8192 + 16*tid of a 16KB (256x32 bf16) half
  const int srow = tid >> 2;                        // 0..127 (+ c*128)
  const int scol = (((tid & 3) ^ (srow & 3)) << 3); // swizzled source col (elems)
  const unsigned short* gA0 = Ae + (size_t)(bm + srow) * K + scol;
  const unsigned short* gA1 = Ae + (size_t)(bm + 128 + srow) * K + scol;
  const unsigned short* gB0 = Be + (size_t)(bn + srow) * K + scol;
  const unsigned short* gB1 = Be + (size_t)(bn + 128 + srow) * K + scol;

  // fragment read offsets (ushorts), swizzle folded in (row&3 == l15&3)
  const int fcol = (((lane >> 4) ^ (l15 & 3)) << 3);
  const int aOff = (wr * 128 + l15) * 32 + fcol;
  const int bOff = 8192 + (wc * 64 + l15) * 32 + fcol;

  // prologue: stage tiles 0..2 (12 gld16/thread in flight)
#pragma unroll
  for (int p = 0; p < 3; ++p) {
    char* base = (char*)lds + p * 32768 + wid * 1024;
    const int k = p << 5;
    gld16(gA0 + k, base);
    gld16(gA1 + k, base + 8192);
    gld16(gB0 + k, base + 16384);
    gld16(gB1 + k, base + 24576);
  }

  for (int t = 0; t < NT; ++t) {
    __builtin_amdgcn_sched_barrier(0);
    if (t + 2 < NT)
      asm volatile("s_waitcnt vmcnt(8) lgkmcnt(0)" ::: "memory");
    else if (t + 1 < NT)
      asm volatile("s_waitcnt vmcnt(4) lgkmcnt(0)" ::: "memory");
    else
      asm volatile("s_waitcnt vmcnt(0) lgkmcnt(0)" ::: "memory");
    __builtin_amdgcn_s_barrier();
    __builtin_amdgcn_sched_barrier(0);

    const unsigned short* ls = lds + (t & 3) * 16384;
    const unsigned short* la = ls + aOff;
    const unsigned short* lb = ls + bOff;
    char* sb = (char*)lds + ((t + 3) & 3) * 32768 + wid * 1024;
    const int kst = (t + 3) << 5;
    const bool doS = (t + 3) < NT; // uniform

    bf16x8 a0, a1, bq0, bq1, bq2, bq3;
    // ---- phase 0: stage A-half0(t+3); read B frags + A mi0,1; MFMA mi0,1 ----
    if (doS) gld16(gA0 + kst, sb);
    bq0 = *(const bf16x8*)(lb);
    bq1 = *(const bf16x8*)(lb + 512);
    bq2 = *(const bf16x8*)(lb + 1024);
    bq3 = *(const bf16x8*)(lb + 1536);
    a0 = *(const bf16x8*)(la);
    a1 = *(const bf16x8*)(la + 512);
    __builtin_amdgcn_s_setprio(1);
    acc[0][0] = MF(a0, bq0, acc[0][0]); acc[0][1] = MF(a0, bq1, acc[0][1]);
    acc[0][2] = MF(a0, bq2, acc[0][2]); acc[0][3] = MF(a0, bq3, acc[0][3]);
    acc[1][0] = MF(a1, bq0, acc[1][0]); acc[1][1] = MF(a1, bq1, acc[1][1]);
    acc[1][2] = MF(a1, bq2, acc[1][2]); acc[1][3] = MF(a1, bq3, acc[1][3]);
    __builtin_amdgcn_s_setprio(0);
    // ---- phase 1 ----
    if (doS) gld16(gA1 + kst, sb + 8192);
    a0 = *(const bf16x8*)(la + 1024);
    a1 = *(const bf16x8*)(la + 1536);
    __builtin_amdgcn_s_setprio(1);
    acc[2][0] = MF(a0, bq0, acc[2][0]); acc[2][1] = MF(a0, bq1, acc[2][1]);
    acc[2][2] = MF(a0, bq2, acc[2][2]); acc[2][3] = MF(a0, bq3, acc[2][3]);
    acc[3][0] = MF(a1, bq0, acc[3][0]); acc[3][1] = MF(a1, bq1, acc[3][1]);
    acc[3][2] = MF(a1, bq2, acc[3][2]); acc[3][3] = MF(a1, bq3, acc[3][3]);
    __builtin_amdgcn_s_setprio(0);
    // ---- phase 2 ----
    if (doS) gld16(gB0 + kst, sb + 16384);
    a0 = *(const bf16x8*)(la + 2048);
    a1 = *(const bf16x8*)(la + 2560);
    __builtin_amdgcn_s_setprio(1);
    acc[4][0] = MF(a0, bq0, acc[4][0]); acc[4][1] = MF(a0, bq1, acc[4][1]);
    acc[4][2] = MF(a0, bq2, acc[4][2]); acc[4][3] = MF(a0, bq3, acc[4][3]);
    acc[5][0] = MF(a1, bq0, acc[5][0]); acc[5][1] = MF(a1, bq1, acc[5][1]);
    acc[5][2] = MF(a1, bq2, acc[5][2]); acc[5][3] = MF(a1, bq3, acc[5][3]);
    __builtin_amdgcn_s_setprio(0);
    // ---- phase 3 ----
    if (doS) gld16(gB1 + kst, sb + 24576);
    a0 = *(const bf16x8*)(la + 3072);
    a1 = *(const bf16x8*)(la + 3584);
    __builtin_amdgcn_s_setprio(1);
    acc[6][0] = MF(a0, bq0, acc[6][0]); acc[6][1] = MF(a0, bq1, acc[6][1]);
    acc[6][2] = MF(a0, bq2, acc[6][2]); acc[6][3] = MF(a0, bq3, acc[6][3]);
    acc[7][0] = MF(a1, bq0, acc[7][0]); acc[7][1] = MF(a1, bq1, acc[7][1]);
    acc[7][2] = MF(a1, bq2, acc[7][2]); acc[7][3] = MF(a1, bq3, acc[7][3]);
    __builtin_amdgcn_s_setprio(0);
  }

  // epilogue: frag D[row=(lane>>4)*4+r][col=lane&15]
  const int orow0 = bm + wr * 128 + ((lane >> 4) << 2);
  const int ocol0 = bn + wc * 64 + l15;
  float bv[4];
#pragma unroll
  for (int ni = 0; ni < 4; ++ni) bv[ni] = be[ocol0 + ni * 16];

  if (MODE == 0) {
    unsigned short* O = (unsigned short*)Out + (size_t)ez * oStride;
#pragma unroll
    for (int mi = 0; mi < 8; ++mi)
#pragma unroll
      for (int r = 0; r < 4; ++r) {
        const size_t rowoff = (size_t)(orow0 + mi * 16 + r) * N;
#pragma unroll
        for (int ni = 0; ni < 4; ++ni) {
          float v = acc[mi][ni][r] + bv[ni];
          O[rowoff + ocol0 + ni * 16] = f2bf(gelu_f(v));
        }
      }
  } else {
    float* O = (float*)Out + (size_t)e * oStride;
#pragma unroll
    for (int mi = 0; mi < 8; ++mi)
#pragma unroll
      for (int r = 0; r < 4; ++r) {
        const size_t rowoff = (size_t)(orow0 + mi * 16 + r) * N;
#pragma unroll
        for (int ni = 0; ni < 4; ++ni) {
          O[rowoff + ocol0 + ni * 16] = acc[mi][ni][r] + bv[ni];
        }
      }
  }
}

extern "C" void kernel_launch(void* const* d_in, const int* in_sizes, int n_in,
                              void* d_out, int out_size, void* d_ws, size_t ws_size,
                              hipStream_t stream) {
  const float* x = (const float*)d_in[0];
  const float* w1 = (const float*)d_in[1];
  const float* b1 = (const float*)d_in[2];
  const float* w2 = (const float*)d_in[3];
  const float* b2 = (const float*)d_in[4];

  char* ws = (char*)d_ws;
  unsigned short* xbf = (unsigned short*)ws;               // 64 MiB
  unsigned short* w1t = (unsigned short*)(ws + 67108864);  // 64 MiB  [E][F][D]
  unsigned short* w2t = (unsigned short*)(ws + 134217728); // 64 MiB  [E][D][F]
  unsigned short* h   = (unsigned short*)(ws + 201326592); // 256 MiB (full mode)

  experts_convert<<<16384, 256, 0, stream>>>(x, xbf, 4194304L);
  experts_transpose64<<<dim3(FF / 64, DD / 64, NE), 256, 0, stream>>>(w1, w1t, DD, FF);
  experts_transpose64<<<dim3(DD / 64, FF / 64, NE), 256, 0, stream>>>(w2, w2t, FF, DD);

  const bool full = ws_size >= 469762048ull;
  if (full) {
    // GEMM1: h[e] = gelu(x[e] @ w1[e] + b1[e])   M=4096 K=1024 N=4096
    experts_gemm8<0><<<dim3(FF / 256, MPE / 256, NE), 512, 0, stream>>>(
        xbf, w1t, b1, h, DD, FF, 0, (size_t)MPE * DD, (size_t)MPE * FF);
    // GEMM2: out[e] = h[e] @ w2[e] + b2[e]       M=4096 K=4096 N=1024
    experts_gemm8<1><<<dim3(DD / 256, MPE / 256, NE), 512, 0, stream>>>(
        h, w2t, b2, d_out, FF, DD, 0, (size_t)MPE * FF, (size_t)MPE * DD);
  } else {
    for (int e = 0; e < NE; ++e) {
      experts_gemm8<0><<<dim3(FF / 256, MPE / 256, 1), 512, 0, stream>>>(
          xbf + (size_t)e * MPE * DD, w1t, b1, h, DD, FF, e, 0, 0);
      experts_gemm8<1><<<dim3(DD / 256, MPE / 256, 1), 512, 0, stream>>>(
          h, w2t, b2, d_out, FF, DD, e, 0, (size_t)MPE * DD);
    }
  }
}